// Round 14
// baseline (212.607 us; speedup 1.0000x reference)
//
#include <hip/hip_runtime.h>

// ConvSBS fused, R12: R10's 4-px-granular high-occupancy structure (measured
// 36% occupancy) with the register footprint cut to ~125 so (64,3)'s cap=170
// does NOT spill (R10/R11 regression root-cause: scratch spill, WRITE_SIZE
// 63-179MB). Cuts: ch1 prefetch held as f16 h4 (32->16 regs), ch0 as fp16,
// stage-A B-frags via v_pk_mul_f16; single live E-read group; bpermute
// epilogue (R11-verified) instead of sbuf round-trip.
//  stage A: t[qlr, px] = W(512x16).P(16x4) -> tbuf   [R6-verified layout]
//  stage B: Ct = M1T.M0T, D = M2.M3T (K=8 pad)       [R7b-verified layout]
//  stage E: 4 px per MFMA chain, block-diag batching  [R7b-verified layout]

typedef __fp16 h2 __attribute__((ext_vector_type(2)));
typedef __fp16 h4 __attribute__((ext_vector_type(4)));
typedef float  f4 __attribute__((ext_vector_type(4)));

#define NB 8
#define NH 128
#define NW 128
#define HO 127
#define WO 127
#define CH1_OFF (NB*NH*NW*4)   // 524288 floats
#define PXSTR 648              // halfs per px slot: 640 data + 8 pad
#define ZOFF  640              // zeroed 4-half pad inside each slot
#define CDROW 68               // C'/D' row stride (halfs)
#define CDSTR 544              // per-px C'/D' stride = 8*68

#define PIN() asm volatile("" ::: "memory")
#define PKRTZ(a, b) __builtin_amdgcn_cvt_pkrtz((a), (b))

__device__ __forceinline__ f4 mfma16(h4 a, h4 b, f4 c) {
  return __builtin_amdgcn_mfma_f32_16x16x16f16(a, b, c, 0, 0, 0);
}

__global__ __launch_bounds__(64, 3)
void convsbs_fused(const float* __restrict__ ch,
                   const float* __restrict__ cores,
                   float* __restrict__ out) {
  const int lane = threadIdx.x & 63;
  const int quad = lane >> 4;   // MFMA k-group / C-row group
  const int nn   = lane & 15;   // MFMA m/n index
  const f4 F4Z = {0.f, 0.f, 0.f, 0.f};

  __shared__ __align__(16) __fp16 tbuf[4 * PXSTR];   // 5184 B
  __shared__ __align__(16) __fp16 cdb[4 * CDSTR];    // 4352 B

  // zero the K=8 pad target in each px slot (read by quads 2,3 in stage B)
  if (lane < 4) *(h4*)(tbuf + lane * PXSTR + ZOFF) = (h4){0, 0, 0, 0};
  PIN();

  // stage-A write base: 4-px tile -> cols nn<4 real, rest masked
  __fp16* wrbase = tbuf + nn * PXSTR + quad * 4;
  const bool wr = (nn < 4);

  // ---- W as 32 A-fragments (R5b/R6-verified); 64 VGPRs
  h4 wf[4][8];
#pragma unroll
  for (int c = 0; c < 4; ++c)
#pragma unroll
    for (int bi = 0; bi < 8; ++bi) {
      const int rowIdx = bi * 16 + nn;
      const int q  = rowIdx >> 6;
      const int ua = (rowIdx >> 3) & 7;
      const int ub = rowIdx & 7;
      const int l = (c & 1) ? ub : ua;
      const int r = (c & 1) ? ua : ub;
      const float4 wv = *(const float4*)(
          cores + ((((c * 2 + q) * 8 + l) * 8 + r) << 4) + quad * 4);
      h2 p0 = PKRTZ(wv.x, wv.y), p1 = PKRTZ(wv.z, wv.w);
      wf[c][bi] = (h4){p0[0], p0[1], p1[0], p1[1]};
    }

  // ---- hoisted, lane-constant stage-B/E LDS offsets (halfs) [R7b-verified]
  const int hq = nn >> 3, hb = nn & 7;
  const int ctA = (quad < 2) ? ((2 + hq) * 80 + hb * 8 + quad * 4) : ZOFF;
  const int ctB = (quad < 2) ? ( hq      * 80 + hb * 8 + quad * 4) : ZOFF;
  const int dA  = (quad < 2) ? ((4 + hq) * 80 + hb * 8 + quad * 4) : ZOFF;
  const int dB  = (quad < 2) ? ((6 + hq) * 80 + hb * 8 + quad * 4) : ZOFF;
  const int ctW = (hq * 2 + (quad >> 1)) * CDROW + hb * 8 + (quad & 1) * 4;
  const int dW  = (4 + (quad >> 1) * 2 + hq) * CDROW + hb * 8 + (quad & 1) * 4;
  const int eA  = (nn >> 2) * CDSTR + (nn & 3) * CDROW + quad * 4;
  const int eB  = (nn >> 2) * CDSTR + (4 + (nn & 3)) * CDROW + quad * 4;
  // bpermute epilogue (R11-verified): out-lane (px=quad, pq=nn>>2, rs=nn&3)
  // pulls e[pq] from source lane 20*px+rs
  const int spq  = (lane >> 2) & 3;
  const int bidx = 4 * (20 * (lane >> 4) + (lane & 3));

  // block = (b, y, x-quarter of 32)
  const int blk = blockIdx.x;
  const int by  = blk >> 2;
  const int b   = by / 127;
  const int y   = by - b * 127;
  const int xq  = (blk & 3) * 32;
  const float* rowbase = ch + (size_t)((b * NH + y) * NW) * 4;
  float* obase = out + (size_t)((b * HO + y) * WO) * 16;

  __fp16 a0h[2][4];   // ch0[a=quad] as f16 (4 regs)
  h4     a1h[2][4];   // ch1[0..3]  as f16 (16 regs)
  auto loadch = [&](int xtile, int bufi) {
#pragma unroll
    for (int c = 0; c < 4; ++c) {
      int col = xtile + (nn & 3) + (c & 1);   // px = nn&3 (cols >=4 garbage)
      col = col > 127 ? 127 : col;
      const float* cp = rowbase + (((c >> 1) * NW) + col) * 4;
      const float  s  = cp[quad];
      const float4 v  = *(const float4*)(cp + CH1_OFF);
      a0h[bufi][c] = (__fp16)s;
      h2 p0 = PKRTZ(v.x, v.y), p1 = PKRTZ(v.z, v.w);
      a1h[bufi][c] = (h4){p0[0], p0[1], p1[0], p1[1]};
    }
  };

  // stage A: 4-px t-tile -> tbuf (32 MFMA + 32 masked b64 writes)
  auto stageA = [&](int bufi) {
    h4 bf[4];
#pragma unroll
    for (int c = 0; c < 4; ++c) {
      const __fp16 s = a0h[bufi][c];
      const h4 aa = {s, s, s, s};
      bf[c] = aa * a1h[bufi][c];          // v_pk_mul_f16 x2
    }
#pragma unroll
    for (int c = 0; c < 4; ++c)
#pragma unroll
      for (int bi = 0; bi < 8; ++bi) {
        f4 acc = mfma16(wf[c][bi], bf[c], F4Z);
        h2 p0 = PKRTZ(acc[0], acc[1]), p1 = PKRTZ(acc[2], acc[3]);
        if (wr)
          *(h4*)(wrbase + c * 160 + bi * 16 + (bi >= 4 ? 16 : 0)) =
              (h4){p0[0], p0[1], p1[0], p1[1]};
      }
  };

  // stage B: 4 px, 8 independent read->MFMA->write chains -> cdb
  auto stageB = [&]() {
#pragma unroll
    for (int p4 = 0; p4 < 4; ++p4) {
      const __fp16* slot = tbuf + p4 * PXSTR;
      __fp16* cd = cdb + p4 * CDSTR;
      h4 a1f = *(const h4*)(slot + ctA);
      h4 b1f = *(const h4*)(slot + ctB);
      f4 c0 = mfma16(a1f, b1f, F4Z);
      h2 u0 = PKRTZ(c0[0], c0[1]), u1 = PKRTZ(c0[2], c0[3]);
      *(h4*)(cd + ctW) = (h4){u0[0], u0[1], u1[0], u1[1]};
      h4 a2f = *(const h4*)(slot + dA);
      h4 b2f = *(const h4*)(slot + dB);
      f4 d0 = mfma16(a2f, b2f, F4Z);
      h2 v0 = PKRTZ(d0[0], d0[1]), v1 = PKRTZ(d0[2], d0[3]);
      *(h4*)(cd + dW) = (h4){v0[0], v0[1], v1[0], v1[1]};
    }
  };

  // prologue: tile 0 through A and B; channels for tile 1 prefetched
  loadch(xq, 0);
  stageA(0);
  loadch(xq + 4, 1);
  PIN();
  stageB();
  PIN();

#pragma unroll 1
  for (int k = 0; k < 8; ++k) {
    // 1. E-reads for tile k (cdb written by B last iteration / prologue)
    h4 ea[4], eb[4];
#pragma unroll
    for (int kb = 0; kb < 4; ++kb) {
      ea[kb] = *(const h4*)(cdb + eA + kb * 16);
      eb[kb] = *(const h4*)(cdb + eB + kb * 16);
    }
    PIN();

    // 2. stage A(k+1): 32 independent MFMAs + writes hide the E-read latency
    if (k < 7) {
      stageA((k + 1) & 1);
      if (k < 6) loadch(xq + (k + 2) * 4, k & 1);
    }
    PIN();

    // 3. E MFMAs (two independent 2-chains) + bpermute transpose + store
    {
      f4 e0 = mfma16(ea[0], eb[0], F4Z);
      f4 e1 = mfma16(ea[1], eb[1], F4Z);
      e0 = mfma16(ea[2], eb[2], e0);
      e1 = mfma16(ea[3], eb[3], e1);
      const f4 e = e0 + e1;
      float r0 = __int_as_float(__builtin_amdgcn_ds_bpermute(bidx, __float_as_int(e[0])));
      float r1 = __int_as_float(__builtin_amdgcn_ds_bpermute(bidx, __float_as_int(e[1])));
      float r2 = __int_as_float(__builtin_amdgcn_ds_bpermute(bidx, __float_as_int(e[2])));
      float r3 = __int_as_float(__builtin_amdgcn_ds_bpermute(bidx, __float_as_int(e[3])));
      const float v01 = (spq & 1) ? r1 : r0;
      const float v23 = (spq & 1) ? r3 : r2;
      const float v   = (spq & 2) ? v23 : v01;
      const int x4 = xq + k * 4 + quad;
      if (x4 < WO) obase[x4 * 16 + nn] = v;
    }
    PIN();

    // 4. stage B(k+1): tbuf (step-2 writes, in-order safe) -> cdb
    //    (cdb WAR vs step-1 reads is safe: wave DS ops execute in order)
    if (k < 7) stageB();
    PIN();
  }
}

extern "C" void kernel_launch(void* const* d_in, const int* in_sizes, int n_in,
                              void* d_out, int out_size, void* d_ws, size_t ws_size,
                              hipStream_t stream) {
  (void)in_sizes; (void)n_in; (void)d_ws; (void)ws_size; (void)out_size;
  const float* ch    = (const float*)d_in[0];  // [2,8,128,128,4] f32
  const float* cores = (const float*)d_in[1];  // [4,2,8,8,4,4]   f32
  float* out = (float*)d_out;                  // [8,127,127,16]  f32
  convsbs_fused<<<8 * 127 * 4, 64, 0, stream>>>(ch, cores, out);
}

// Round 15
// 112.788 us; speedup vs baseline: 1.8850x; 1.8850x over previous
//
#include <hip/hip_runtime.h>

// ConvSBS fused, R13: R12's 4-px high-occupancy structure with the ONE bug
// fixed: R12 built stage-A B-frags with __fp16 ext-vector multiplies, which
// HIP lowers via f32 promote/demote scalarization (~300 extra VALU inst/px,
// VALUBusy 14->30%, dur 83->185us). Channels back to f32 regs; B-frags via
// f32 mul + cvt_pkrtz (R6/R9/R10-verified path). Footprint ~140 regs fits
// (64,3) cap=170 -> no spill (R10: cap128 spilled; R11: ~175 spilled).
//  stage A: t[qlr, px] = W(512x16).P(16x4) -> tbuf   [R6-verified layout]
//  stage B: Ct = M1T.M0T, D = M2.M3T (K=8 pad)       [R7b-verified layout]
//  stage E: 4 px per MFMA chain, block-diag batching  [R7b-verified layout]
//  epilogue: 4x ds_bpermute transpose + coalesced store [R11-verified]

typedef __fp16 h2 __attribute__((ext_vector_type(2)));
typedef __fp16 h4 __attribute__((ext_vector_type(4)));
typedef float  f4 __attribute__((ext_vector_type(4)));

#define NB 8
#define NH 128
#define NW 128
#define HO 127
#define WO 127
#define CH1_OFF (NB*NH*NW*4)   // 524288 floats
#define PXSTR 648              // halfs per px slot: 640 data + 8 pad
#define ZOFF  640              // zeroed 4-half pad inside each slot
#define CDROW 68               // C'/D' row stride (halfs)
#define CDSTR 544              // per-px C'/D' stride = 8*68

#define PIN() asm volatile("" ::: "memory")
#define PKRTZ(a, b) __builtin_amdgcn_cvt_pkrtz((a), (b))

__device__ __forceinline__ f4 mfma16(h4 a, h4 b, f4 c) {
  return __builtin_amdgcn_mfma_f32_16x16x16f16(a, b, c, 0, 0, 0);
}

__global__ __launch_bounds__(64, 3)
void convsbs_fused(const float* __restrict__ ch,
                   const float* __restrict__ cores,
                   float* __restrict__ out) {
  const int lane = threadIdx.x & 63;
  const int quad = lane >> 4;   // MFMA k-group / C-row group
  const int nn   = lane & 15;   // MFMA m/n index
  const f4 F4Z = {0.f, 0.f, 0.f, 0.f};

  __shared__ __align__(16) __fp16 tbuf[4 * PXSTR];   // 5184 B
  __shared__ __align__(16) __fp16 cdb[4 * CDSTR];    // 4352 B

  // zero the K=8 pad target in each px slot (read by quads 2,3 in stage B)
  if (lane < 4) *(h4*)(tbuf + lane * PXSTR + ZOFF) = (h4){0, 0, 0, 0};
  PIN();

  // stage-A write base: 4-px tile -> cols nn<4 real, rest masked
  __fp16* wrbase = tbuf + nn * PXSTR + quad * 4;
  const bool wr = (nn < 4);

  // ---- W as 32 A-fragments (R5b/R6-verified); 64 VGPRs
  h4 wf[4][8];
#pragma unroll
  for (int c = 0; c < 4; ++c)
#pragma unroll
    for (int bi = 0; bi < 8; ++bi) {
      const int rowIdx = bi * 16 + nn;
      const int q  = rowIdx >> 6;
      const int ua = (rowIdx >> 3) & 7;
      const int ub = rowIdx & 7;
      const int l = (c & 1) ? ub : ua;
      const int r = (c & 1) ? ua : ub;
      const float4 wv = *(const float4*)(
          cores + ((((c * 2 + q) * 8 + l) * 8 + r) << 4) + quad * 4);
      h2 p0 = PKRTZ(wv.x, wv.y), p1 = PKRTZ(wv.z, wv.w);
      wf[c][bi] = (h4){p0[0], p0[1], p1[0], p1[1]};
    }

  // ---- hoisted, lane-constant stage-B/E LDS offsets (halfs) [R7b-verified]
  const int hq = nn >> 3, hb = nn & 7;
  const int ctA = (quad < 2) ? ((2 + hq) * 80 + hb * 8 + quad * 4) : ZOFF;
  const int ctB = (quad < 2) ? ( hq      * 80 + hb * 8 + quad * 4) : ZOFF;
  const int dA  = (quad < 2) ? ((4 + hq) * 80 + hb * 8 + quad * 4) : ZOFF;
  const int dB  = (quad < 2) ? ((6 + hq) * 80 + hb * 8 + quad * 4) : ZOFF;
  const int ctW = (hq * 2 + (quad >> 1)) * CDROW + hb * 8 + (quad & 1) * 4;
  const int dW  = (4 + (quad >> 1) * 2 + hq) * CDROW + hb * 8 + (quad & 1) * 4;
  const int eA  = (nn >> 2) * CDSTR + (nn & 3) * CDROW + quad * 4;
  const int eB  = (nn >> 2) * CDSTR + (4 + (nn & 3)) * CDROW + quad * 4;
  // bpermute epilogue (R11-verified): out-lane (px=quad, pq=nn>>2, rs=nn&3)
  // pulls e[pq] from source lane 20*px+rs
  const int spq  = (lane >> 2) & 3;
  const int bidx = 4 * (20 * (lane >> 4) + (lane & 3));

  // block = (b, y, x-quarter of 32)
  const int blk = blockIdx.x;
  const int by  = blk >> 2;
  const int b   = by / 127;
  const int y   = by - b * 127;
  const int xq  = (blk & 3) * 32;
  const float* rowbase = ch + (size_t)((b * NH + y) * NW) * 4;
  float* obase = out + (size_t)((b * HO + y) * WO) * 16;

  float  a0[2][4];
  float4 a1[2][4];
  auto loadch = [&](int xtile, int bufi) {
#pragma unroll
    for (int c = 0; c < 4; ++c) {
      int col = xtile + (nn & 3) + (c & 1);   // px = nn&3 (cols >=4 garbage)
      col = col > 127 ? 127 : col;
      const float* cp = rowbase + (((c >> 1) * NW) + col) * 4;
      a0[bufi][c] = cp[quad];
      a1[bufi][c] = *(const float4*)(cp + CH1_OFF);
    }
  };

  // stage A: 4-px t-tile -> tbuf (32 MFMA + 32 masked b64 writes)
  // B-frags in f32 + PKRTZ (NOT __fp16 vector math - R12's 2.2x regression)
  auto stageA = [&](int bufi) {
    h4 bf[4];
#pragma unroll
    for (int c = 0; c < 4; ++c) {
      const float s = a0[bufi][c];
      const float4 v = a1[bufi][c];
      h2 p0 = PKRTZ(s * v.x, s * v.y), p1 = PKRTZ(s * v.z, s * v.w);
      bf[c] = (h4){p0[0], p0[1], p1[0], p1[1]};
    }
#pragma unroll
    for (int c = 0; c < 4; ++c)
#pragma unroll
      for (int bi = 0; bi < 8; ++bi) {
        f4 acc = mfma16(wf[c][bi], bf[c], F4Z);
        h2 p0 = PKRTZ(acc[0], acc[1]), p1 = PKRTZ(acc[2], acc[3]);
        if (wr)
          *(h4*)(wrbase + c * 160 + bi * 16 + (bi >= 4 ? 16 : 0)) =
              (h4){p0[0], p0[1], p1[0], p1[1]};
      }
  };

  // stage B: 4 px, 8 independent read->MFMA->write chains -> cdb
  auto stageB = [&]() {
#pragma unroll
    for (int p4 = 0; p4 < 4; ++p4) {
      const __fp16* slot = tbuf + p4 * PXSTR;
      __fp16* cd = cdb + p4 * CDSTR;
      h4 a1f = *(const h4*)(slot + ctA);
      h4 b1f = *(const h4*)(slot + ctB);
      f4 c0 = mfma16(a1f, b1f, F4Z);
      h2 u0 = PKRTZ(c0[0], c0[1]), u1 = PKRTZ(c0[2], c0[3]);
      *(h4*)(cd + ctW) = (h4){u0[0], u0[1], u1[0], u1[1]};
      h4 a2f = *(const h4*)(slot + dA);
      h4 b2f = *(const h4*)(slot + dB);
      f4 d0 = mfma16(a2f, b2f, F4Z);
      h2 v0 = PKRTZ(d0[0], d0[1]), v1 = PKRTZ(d0[2], d0[3]);
      *(h4*)(cd + dW) = (h4){v0[0], v0[1], v1[0], v1[1]};
    }
  };

  // prologue: tile 0 through A and B; channels for tile 1 prefetched
  loadch(xq, 0);
  stageA(0);
  loadch(xq + 4, 1);
  PIN();
  stageB();
  PIN();

#pragma unroll 1
  for (int k = 0; k < 8; ++k) {
    // 1. E-reads for tile k (cdb written by B last iteration / prologue)
    h4 ea[4], eb[4];
#pragma unroll
    for (int kb = 0; kb < 4; ++kb) {
      ea[kb] = *(const h4*)(cdb + eA + kb * 16);
      eb[kb] = *(const h4*)(cdb + eB + kb * 16);
    }
    PIN();

    // 2. stage A(k+1): 32 independent MFMAs + writes hide the E-read latency
    if (k < 7) {
      stageA((k + 1) & 1);
      if (k < 6) loadch(xq + (k + 2) * 4, k & 1);
    }
    PIN();

    // 3. E MFMAs (two independent 2-chains) + bpermute transpose + store
    {
      f4 e0 = mfma16(ea[0], eb[0], F4Z);
      f4 e1 = mfma16(ea[1], eb[1], F4Z);
      e0 = mfma16(ea[2], eb[2], e0);
      e1 = mfma16(ea[3], eb[3], e1);
      const f4 e = e0 + e1;
      float r0 = __int_as_float(__builtin_amdgcn_ds_bpermute(bidx, __float_as_int(e[0])));
      float r1 = __int_as_float(__builtin_amdgcn_ds_bpermute(bidx, __float_as_int(e[1])));
      float r2 = __int_as_float(__builtin_amdgcn_ds_bpermute(bidx, __float_as_int(e[2])));
      float r3 = __int_as_float(__builtin_amdgcn_ds_bpermute(bidx, __float_as_int(e[3])));
      const float v01 = (spq & 1) ? r1 : r0;
      const float v23 = (spq & 1) ? r3 : r2;
      const float v   = (spq & 2) ? v23 : v01;
      const int x4 = xq + k * 4 + quad;
      if (x4 < WO) obase[x4 * 16 + nn] = v;
    }
    PIN();

    // 4. stage B(k+1): tbuf (step-2 writes, in-order safe) -> cdb
    //    (cdb WAR vs step-1 reads is safe: wave DS ops execute in order)
    if (k < 7) stageB();
    PIN();
  }
}

extern "C" void kernel_launch(void* const* d_in, const int* in_sizes, int n_in,
                              void* d_out, int out_size, void* d_ws, size_t ws_size,
                              hipStream_t stream) {
  (void)in_sizes; (void)n_in; (void)d_ws; (void)ws_size; (void)out_size;
  const float* ch    = (const float*)d_in[0];  // [2,8,128,128,4] f32
  const float* cores = (const float*)d_in[1];  // [4,2,8,8,4,4]   f32
  float* out = (float*)d_out;                  // [8,127,127,16]  f32
  convsbs_fused<<<8 * 127 * 4, 64, 0, stream>>>(ch, cores, out);
}

// Round 16
// 95.184 us; speedup vs baseline: 2.2336x; 1.1849x over previous
//
#include <hip/hip_runtime.h>

// ConvSBS fused, R14: R13 with the k-loop FULLY UNROLLED. Root cause of the
// R10/R11/R13 "spills": `#pragma unroll 1` made bufi=(k+1)&1 a runtime value,
// so the channel-prefetch arrays were dynamically indexed -> allocated to
// scratch (WRITE_SIZE 63-179MB of scratch traffic). Full unroll makes every
// index compile-time -> mem2reg promotes arrays to registers (R9/R12
// precedent: compile-time-indexed structures show WRITE ~= output).
//  stage A: t[qlr, px] = W(512x16).P(16x4) -> tbuf   [R6-verified layout]
//  stage B: Ct = M1T.M0T, D = M2.M3T (K=8 pad)       [R7b-verified layout]
//  stage E: 4 px per MFMA chain, block-diag batching  [R7b-verified layout]
//  epilogue: 4x ds_bpermute transpose + coalesced store [R11-verified]

typedef __fp16 h2 __attribute__((ext_vector_type(2)));
typedef __fp16 h4 __attribute__((ext_vector_type(4)));
typedef float  f4 __attribute__((ext_vector_type(4)));

#define NB 8
#define NH 128
#define NW 128
#define HO 127
#define WO 127
#define CH1_OFF (NB*NH*NW*4)   // 524288 floats
#define PXSTR 648              // halfs per px slot: 640 data + 8 pad
#define ZOFF  640              // zeroed 4-half pad inside each slot
#define CDROW 68               // C'/D' row stride (halfs)
#define CDSTR 544              // per-px C'/D' stride = 8*68

#define PIN() asm volatile("" ::: "memory")
#define PKRTZ(a, b) __builtin_amdgcn_cvt_pkrtz((a), (b))

__device__ __forceinline__ f4 mfma16(h4 a, h4 b, f4 c) {
  return __builtin_amdgcn_mfma_f32_16x16x16f16(a, b, c, 0, 0, 0);
}

__global__ __launch_bounds__(64, 3)
void convsbs_fused(const float* __restrict__ ch,
                   const float* __restrict__ cores,
                   float* __restrict__ out) {
  const int lane = threadIdx.x & 63;
  const int quad = lane >> 4;   // MFMA k-group / C-row group
  const int nn   = lane & 15;   // MFMA m/n index
  const f4 F4Z = {0.f, 0.f, 0.f, 0.f};

  __shared__ __align__(16) __fp16 tbuf[4 * PXSTR];   // 5184 B
  __shared__ __align__(16) __fp16 cdb[4 * CDSTR];    // 4352 B

  // zero the K=8 pad target in each px slot (read by quads 2,3 in stage B)
  if (lane < 4) *(h4*)(tbuf + lane * PXSTR + ZOFF) = (h4){0, 0, 0, 0};
  PIN();

  // stage-A write base: 4-px tile -> cols nn<4 real, rest masked
  __fp16* wrbase = tbuf + nn * PXSTR + quad * 4;
  const bool wr = (nn < 4);

  // ---- W as 32 A-fragments (R5b/R6-verified); 64 VGPRs
  h4 wf[4][8];
#pragma unroll
  for (int c = 0; c < 4; ++c)
#pragma unroll
    for (int bi = 0; bi < 8; ++bi) {
      const int rowIdx = bi * 16 + nn;
      const int q  = rowIdx >> 6;
      const int ua = (rowIdx >> 3) & 7;
      const int ub = rowIdx & 7;
      const int l = (c & 1) ? ub : ua;
      const int r = (c & 1) ? ua : ub;
      const float4 wv = *(const float4*)(
          cores + ((((c * 2 + q) * 8 + l) * 8 + r) << 4) + quad * 4);
      h2 p0 = PKRTZ(wv.x, wv.y), p1 = PKRTZ(wv.z, wv.w);
      wf[c][bi] = (h4){p0[0], p0[1], p1[0], p1[1]};
    }

  // ---- hoisted, lane-constant stage-B/E LDS offsets (halfs) [R7b-verified]
  const int hq = nn >> 3, hb = nn & 7;
  const int ctA = (quad < 2) ? ((2 + hq) * 80 + hb * 8 + quad * 4) : ZOFF;
  const int ctB = (quad < 2) ? ( hq      * 80 + hb * 8 + quad * 4) : ZOFF;
  const int dA  = (quad < 2) ? ((4 + hq) * 80 + hb * 8 + quad * 4) : ZOFF;
  const int dB  = (quad < 2) ? ((6 + hq) * 80 + hb * 8 + quad * 4) : ZOFF;
  const int ctW = (hq * 2 + (quad >> 1)) * CDROW + hb * 8 + (quad & 1) * 4;
  const int dW  = (4 + (quad >> 1) * 2 + hq) * CDROW + hb * 8 + (quad & 1) * 4;
  const int eA  = (nn >> 2) * CDSTR + (nn & 3) * CDROW + quad * 4;
  const int eB  = (nn >> 2) * CDSTR + (4 + (nn & 3)) * CDROW + quad * 4;
  // bpermute epilogue (R11-verified): out-lane (px=quad, pq=nn>>2, rs=nn&3)
  // pulls e[pq] from source lane 20*px+rs
  const int spq  = (lane >> 2) & 3;
  const int bidx = 4 * (20 * (lane >> 4) + (lane & 3));

  // block = (b, y, x-quarter of 32)
  const int blk = blockIdx.x;
  const int by  = blk >> 2;
  const int b   = by / 127;
  const int y   = by - b * 127;
  const int xq  = (blk & 3) * 32;
  const float* rowbase = ch + (size_t)((b * NH + y) * NW) * 4;
  float* obase = out + (size_t)((b * HO + y) * WO) * 16;

  float  a0[2][4];
  float4 a1[2][4];
  auto loadch = [&](int xtile, int bufi) {
#pragma unroll
    for (int c = 0; c < 4; ++c) {
      int col = xtile + (nn & 3) + (c & 1);   // px = nn&3 (cols >=4 garbage)
      col = col > 127 ? 127 : col;
      const float* cp = rowbase + (((c >> 1) * NW) + col) * 4;
      a0[bufi][c] = cp[quad];
      a1[bufi][c] = *(const float4*)(cp + CH1_OFF);
    }
  };

  // stage A: 4-px t-tile -> tbuf (32 MFMA + 32 masked b64 writes)
  // B-frags in f32 + PKRTZ (NOT __fp16 vector math - R12's 2.2x regression)
  auto stageA = [&](int bufi) {
    h4 bf[4];
#pragma unroll
    for (int c = 0; c < 4; ++c) {
      const float s = a0[bufi][c];
      const float4 v = a1[bufi][c];
      h2 p0 = PKRTZ(s * v.x, s * v.y), p1 = PKRTZ(s * v.z, s * v.w);
      bf[c] = (h4){p0[0], p0[1], p1[0], p1[1]};
    }
#pragma unroll
    for (int c = 0; c < 4; ++c)
#pragma unroll
      for (int bi = 0; bi < 8; ++bi) {
        f4 acc = mfma16(wf[c][bi], bf[c], F4Z);
        h2 p0 = PKRTZ(acc[0], acc[1]), p1 = PKRTZ(acc[2], acc[3]);
        if (wr)
          *(h4*)(wrbase + c * 160 + bi * 16 + (bi >= 4 ? 16 : 0)) =
              (h4){p0[0], p0[1], p1[0], p1[1]};
      }
  };

  // stage B: 4 px, 8 independent read->MFMA->write chains -> cdb
  auto stageB = [&]() {
#pragma unroll
    for (int p4 = 0; p4 < 4; ++p4) {
      const __fp16* slot = tbuf + p4 * PXSTR;
      __fp16* cd = cdb + p4 * CDSTR;
      h4 a1f = *(const h4*)(slot + ctA);
      h4 b1f = *(const h4*)(slot + ctB);
      f4 c0 = mfma16(a1f, b1f, F4Z);
      h2 u0 = PKRTZ(c0[0], c0[1]), u1 = PKRTZ(c0[2], c0[3]);
      *(h4*)(cd + ctW) = (h4){u0[0], u0[1], u1[0], u1[1]};
      h4 a2f = *(const h4*)(slot + dA);
      h4 b2f = *(const h4*)(slot + dB);
      f4 d0 = mfma16(a2f, b2f, F4Z);
      h2 v0 = PKRTZ(d0[0], d0[1]), v1 = PKRTZ(d0[2], d0[3]);
      *(h4*)(cd + dW) = (h4){v0[0], v0[1], v1[0], v1[1]};
    }
  };

  // prologue: tile 0 through A and B; channels for tile 1 prefetched
  loadch(xq, 0);
  stageA(0);
  loadch(xq + 4, 1);
  PIN();
  stageB();
  PIN();

  // FULLY UNROLLED pixel loop: all bufi/k indices compile-time constants
#pragma unroll
  for (int k = 0; k < 8; ++k) {
    // 1. E-reads for tile k (cdb written by B last iteration / prologue)
    h4 ea[4], eb[4];
#pragma unroll
    for (int kb = 0; kb < 4; ++kb) {
      ea[kb] = *(const h4*)(cdb + eA + kb * 16);
      eb[kb] = *(const h4*)(cdb + eB + kb * 16);
    }
    PIN();

    // 2. stage A(k+1): 32 independent MFMAs + writes hide the E-read latency
    if (k < 7) {
      stageA((k + 1) & 1);
      if (k < 6) loadch(xq + (k + 2) * 4, k & 1);
    }
    PIN();

    // 3. E MFMAs (two independent 2-chains) + bpermute transpose + store
    {
      f4 e0 = mfma16(ea[0], eb[0], F4Z);
      f4 e1 = mfma16(ea[1], eb[1], F4Z);
      e0 = mfma16(ea[2], eb[2], e0);
      e1 = mfma16(ea[3], eb[3], e1);
      const f4 e = e0 + e1;
      float r0 = __int_as_float(__builtin_amdgcn_ds_bpermute(bidx, __float_as_int(e[0])));
      float r1 = __int_as_float(__builtin_amdgcn_ds_bpermute(bidx, __float_as_int(e[1])));
      float r2 = __int_as_float(__builtin_amdgcn_ds_bpermute(bidx, __float_as_int(e[2])));
      float r3 = __int_as_float(__builtin_amdgcn_ds_bpermute(bidx, __float_as_int(e[3])));
      const float v01 = (spq & 1) ? r1 : r0;
      const float v23 = (spq & 1) ? r3 : r2;
      const float v   = (spq & 2) ? v23 : v01;
      const int x4 = xq + k * 4 + quad;
      if (x4 < WO) obase[x4 * 16 + nn] = v;
    }
    PIN();

    // 4. stage B(k+1): tbuf (step-2 writes, in-order safe) -> cdb
    //    (cdb WAR vs step-1 reads is safe: wave DS ops execute in order)
    if (k < 7) stageB();
    PIN();
  }
}

extern "C" void kernel_launch(void* const* d_in, const int* in_sizes, int n_in,
                              void* d_out, int out_size, void* d_ws, size_t ws_size,
                              hipStream_t stream) {
  (void)in_sizes; (void)n_in; (void)d_ws; (void)ws_size; (void)out_size;
  const float* ch    = (const float*)d_in[0];  // [2,8,128,128,4] f32
  const float* cores = (const float*)d_in[1];  // [4,2,8,8,4,4]   f32
  float* out = (float*)d_out;                  // [8,127,127,16]  f32
  convsbs_fused<<<8 * 127 * 4, 64, 0, stream>>>(ch, cores, out);
}